// Round 10
// baseline (267.655 us; speedup 1.0000x reference)
//
#include <hip/hip_runtime.h>

#define EPS_C 0.05f
#define BLOCK 256
#define SUBT 2
#define CHUNK (SUBT * 4096)   /* pass-1 block: 8192 elems, 32/thread */
#define CHUNK2 2048           /* pass-2 block: 2048 elems, 8/thread */

typedef int i4 __attribute__((ext_vector_type(4)));    /* nt-load-compatible */

// Build the 6-entry change table into LDS (thread 0 only; caller syncs).
__device__ __forceinline__ void build_table(const float* bd_p, const float* d_p,
                                            const float* s_p, const float* inc_p,
                                            const float* bi_p, float* cs) {
  if (threadIdx.x == 0) {
    float bd = *bd_p, d = *d_p, s = *s_p, inc = *inc_p, bi = *bi_p;
    cs[0] = 0.0f;                                       // cat 0 (unused)
    cs[1] = fminf(bd, fminf(0.0f, d)) - EPS_C;          // big decrease
    cs[2] = fminf(fmaxf(d, bd + EPS_C), -EPS_C);        // decrease (clip)
    cs[3] = s;                                          // same
    cs[4] = fminf(fmaxf(inc, EPS_C), bi - EPS_C);       // increase (clip)
    cs[5] = fmaxf(bi, fmaxf(0.0f, inc) + EPS_C);        // big increase
    cs[6] = 0.0f; cs[7] = 0.0f;
  }
}

// Pass 1: pack categories to 4b/elem (pack is nibble[e], element order) and
// emit per-1024-elem fine sums + per-block coarse sums. Input loads are
// nontemporal (read-once) to protect pack/L3 residency.
__global__ __launch_bounds__(BLOCK) void k_reduce_pack(
    const int* __restrict__ ann, const float* bd, const float* d,
    const float* s, const float* inc, const float* bi,
    uint2* __restrict__ packed, float* __restrict__ coarse,
    float* __restrict__ fine) {
  __shared__ float cs[8];
  __shared__ float wsum[SUBT * 4];
  build_table(bd, d, s, inc, bi, cs);
  __syncthreads();

  const int b = blockIdx.x, t = threadIdx.x;
  const int lane = t & 63, wid = t >> 6;
  const i4* in4 = (const i4*)(ann + (size_t)b * CHUNK);

#pragma unroll
  for (int j = 0; j < SUBT; ++j) {
    unsigned int w0 = 0u, w1 = 0u;
    float sum = 0.0f;
#pragma unroll
    for (int i = 0; i < 4; ++i) {
      i4 v = __builtin_nontemporal_load(&in4[j * 1024 + t * 4 + i]);
      sum += cs[v.x] + cs[v.y] + cs[v.z] + cs[v.w];
      unsigned int nib = (unsigned)v.x | ((unsigned)v.y << 4) |
                         ((unsigned)v.z << 8) | ((unsigned)v.w << 12);
      if (i < 2) w0 |= nib << ((i & 1) * 16);
      else       w1 |= nib << ((i & 1) * 16);
    }
    packed[(size_t)b * (SUBT * BLOCK) + j * BLOCK + t] = make_uint2(w0, w1);
    // wave sum = fine sum over this wave's 1024 contiguous elems of subtile j
#pragma unroll
    for (int off = 32; off >= 1; off >>= 1) sum += __shfl_down(sum, off, 64);
    if (lane == 0) {
      fine[b * (SUBT * 4) + j * 4 + wid] = sum;
      wsum[j * 4 + wid] = sum;
    }
  }
  __syncthreads();
  if (t == 0) {
    float tot = 0.0f;
#pragma unroll
    for (int i = 0; i < SUBT * 4; ++i) tot += wsum[i];
    coarse[b] = tot;
  }
}

// Pass 2: block b2 covers [b2*2048, +2048). Thread t owns 8 CONTIGUOUS elems
// (one uint of pack), single block scan (one barrier), two float4 stores.
// Per-instruction lanes are 32 B apart; L2 merges to full lines (R5/R7:
// WRITE exactly 131 MB with this family of patterns).
__global__ __launch_bounds__(BLOCK) void k_scan_out(
    const unsigned int* __restrict__ upack, const float* __restrict__ coarse,
    const float* __restrict__ fine, const float* __restrict__ origin,
    const float* bd, const float* d, const float* s, const float* inc,
    const float* bi, float* __restrict__ out, int nb2) {
  __shared__ float cs[8];
  __shared__ float wsum[BLOCK / 64];
  __shared__ float s_base;
  build_table(bd, d, s, inc, bi, cs);
  __syncthreads();

  const int b2 = blockIdx.x, t = threadIdx.x;
  const int lane = t & 63, wid = t >> 6;
  const int cb = b2 >> 2;                 // owning coarse (P1) block
  const int fcnt = 2 * (b2 & 3);          // fine entries before us in cb

  // One uint = this thread's 8 categories (in flight during offset reduce).
  const unsigned int u = upack[(size_t)b2 * 256 + t];

  // Block offset: coarse[0..cb) (<=16 iters, L2/L3-hot) + fine[cb*8..+fcnt).
  float p = 0.0f;
  if (t < fcnt) p = fine[cb * 8 + t];
  for (int i = t; i < cb; i += BLOCK) p += coarse[i];
#pragma unroll
  for (int off = 32; off >= 1; off >>= 1) p += __shfl_down(p, off, 64);

  // Decode 8 categories while the reduce shuffles settle.
  float vals[8];
#pragma unroll
  for (int k = 0; k < 8; ++k) vals[k] = cs[(u >> (4 * k)) & 0xF];
  float run = 0.0f;
#pragma unroll
  for (int i = 0; i < 8; ++i) run += vals[i];

  // Wave scan of per-thread totals.
  float x = run;
#pragma unroll
  for (int off = 1; off < 64; off <<= 1) {
    float y = __shfl_up(x, off, 64);
    if (lane >= off) x += y;
  }
  if (lane == 0) wsum[wid] = p;            // offset partials
  __syncthreads();
  if (t == 0) s_base = *origin + wsum[0] + wsum[1] + wsum[2] + wsum[3];
  __syncthreads();
  if (lane == 63) wsum[wid] = x;           // wave totals for block scan
  __syncthreads();
  float wexcl = 0.0f;
#pragma unroll
  for (int i = 0; i < BLOCK / 64; ++i)
    if (i < wid) wexcl += wsum[i];

  const float off0 = s_base + wexcl + (x - run);  // thread-exclusive prefix

  float4* out4 = (float4*)(out + (size_t)b2 * CHUNK2);
  float r = off0;
  float4 o0, o1;
  o0.x = r; r += vals[0];
  o0.y = r; r += vals[1];
  o0.z = r; r += vals[2];
  o0.w = r; r += vals[3];
  o1.x = r; r += vals[4];
  o1.y = r; r += vals[5];
  o1.z = r; r += vals[6];
  o1.w = r; r += vals[7];
  out4[t * 2 + 0] = o0;
  out4[t * 2 + 1] = o1;

  if (b2 == nb2 - 1 && t == BLOCK - 1)
    out[(size_t)nb2 * CHUNK2] = r;  // out[N] = origin + total sum
}

extern "C" void kernel_launch(void* const* d_in, const int* in_sizes, int n_in,
                              void* d_out, int out_size, void* d_ws, size_t ws_size,
                              hipStream_t stream) {
  const int*   ann    = (const int*)d_in[0];
  const float* origin = (const float*)d_in[1];
  const float* bd     = (const float*)d_in[2];
  const float* dw     = (const float*)d_in[3];
  const float* sw     = (const float*)d_in[4];
  const float* inc    = (const float*)d_in[5];
  const float* bi     = (const float*)d_in[6];
  float* out = (float*)d_out;

  const int N   = in_sizes[0];    // 2^25
  const int nbc = N / CHUNK;      // 4096 coarse blocks
  const int nb2 = N / CHUNK2;     // 16384 scan blocks

  float* coarse = (float*)d_ws;                       // 4096 floats
  float* fine   = (float*)((char*)d_ws + 65536);      // 32768 floats (128 KB)
  uint2* packed = (uint2*)((char*)d_ws + 262144);     // 16.8 MB

  k_reduce_pack<<<nbc, BLOCK, 0, stream>>>(ann, bd, dw, sw, inc, bi,
                                           packed, coarse, fine);
  k_scan_out<<<nb2, BLOCK, 0, stream>>>((const unsigned int*)packed, coarse,
                                        fine, origin, bd, dw, sw, inc, bi,
                                        out, nb2);
}